// Round 8
// baseline (3468.951 us; speedup 1.0000x reference)
//
#include <hip/hip_runtime.h>
#include <hip/hip_fp16.h>
#include <math.h>

#define NUV 200000
#define NIV 100000
#define EV  1000000
#define NQV 100000
#define NC  (3 * NIV + 3 * NUV)   // 900000 nodes (relation-side)
#define EV6 (6 * EV)
#define NSI 8                     // slices of USER table (item-side gathers), 25000 rows = 3.2MB fp16
#define NSU 4                     // slices of ITEM table (user-side gathers), 25000 rows = 3.2MB fp16
#define ITB (3 * NIV * NSI)       // 2,400,000 item-side buckets
#define TOTB (ITB + 3 * NUV * NSU)// 4,800,000 total buckets
#define SLICE_DIV 25000

struct alignas(8) H4 { __half2 a, b; };

// ---------------- fp32 -> fp16 table conversion (both tables) ----------------
__global__ __launch_bounds__(256) void k_tohalf(const float* __restrict__ inu,
                                                const float* __restrict__ ini,
                                                __half* __restrict__ outu,
                                                __half* __restrict__ outi) {
    const int NU4 = NUV * 16;
    const int NTOT = NU4 + NIV * 16;
    int i = blockIdx.x * 256 + threadIdx.x;
    if (i < NTOT) {
        const float* in = (i < NU4) ? inu : ini;
        __half* out = (i < NU4) ? outu : outi;
        int j = (i < NU4) ? i : (i - NU4);
        float4 v = ((const float4*)in)[j];
        H4 o;
        o.a = __floats2half2_rn(v.x, v.y);
        o.b = __floats2half2_rn(v.z, v.w);
        ((H4*)out)[j] = o;
    }
}

// ---------------- bucket histogram + in-bucket rank (all 3 relations) --------
// bucket(item-side, rel k, item i, src-slice su) = (k*NIV+i)*NSI + su
// bucket(user-side, rel k, user u, src-slice si) = ITB + (k*NUV+u)*NSU + si
__global__ __launch_bounds__(256) void k_count(const int* __restrict__ e0,
                                               const int* __restrict__ e1,
                                               const int* __restrict__ e2,
                                               int* __restrict__ cnt,
                                               int* __restrict__ rk_i,
                                               int* __restrict__ rk_u) {
    int k = blockIdx.y;
    const int* ed = (k == 0) ? e0 : (k == 1) ? e1 : e2;
    int e = blockIdx.x * 256 + threadIdx.x;
    if (e < EV) {
        int u = ed[e], i = ed[EV + e];
        int idx1 = (k * NIV + i) * NSI + u / SLICE_DIV;
        int idx2 = ITB + (k * NUV + u) * NSU + i / SLICE_DIV;
        rk_i[(size_t)k * EV + e] = atomicAdd(&cnt[idx1], 1);
        rk_u[(size_t)k * EV + e] = atomicAdd(&cnt[idx2], 1);
    }
}

// ---------------- scan stage 1: per-256 tile exclusive scan ------------------
__global__ __launch_bounds__(256) void k_scan1(const int* __restrict__ cnt,
                                               int* __restrict__ S,
                                               int* __restrict__ bsum) {
    __shared__ int tmp[256];
    int idx = blockIdx.x * 256 + threadIdx.x;
    int v = (idx < TOTB) ? cnt[idx] : 0;
    tmp[threadIdx.x] = v;
    __syncthreads();
    for (int off = 1; off < 256; off <<= 1) {
        int t = (threadIdx.x >= off) ? tmp[threadIdx.x - off] : 0;
        __syncthreads();
        tmp[threadIdx.x] += t;
        __syncthreads();
    }
    if (idx < TOTB) S[idx] = tmp[threadIdx.x] - v;
    if (threadIdx.x == 255) bsum[blockIdx.x] = tmp[255];
}

// ---------------- scan stage 2: single-wave scan of block sums ---------------
__global__ __launch_bounds__(64) void k_scan2(int* __restrict__ bsum, int nb) {
    int lane = threadIdx.x;
    int carry = 0;
    for (int base = 0; base < nb; base += 64) {
        int i = base + lane;
        int v = (i < nb) ? bsum[i] : 0;
        int orig = v;
        #pragma unroll
        for (int off = 1; off < 64; off <<= 1) {
            int t = __shfl_up(v, off, 64);
            if (lane >= off) v += t;
        }
        if (i < nb) bsum[i] = carry + v - orig;  // exclusive
        carry += __shfl(v, 63, 64);
    }
}

// ---------------- scan stage 3: add block offsets, write sentinel ------------
__global__ __launch_bounds__(256) void k_scan3(int* __restrict__ S,
                                               const int* __restrict__ bsum) {
    int idx = blockIdx.x * 256 + threadIdx.x;
    if (idx < TOTB) S[idx] += bsum[blockIdx.x];
    if (idx == 0) S[TOTB] = EV6;
}

// ---------------- per-node 1/sqrt(deg) from bucket scan ----------------------
__global__ __launch_bounds__(256) void k_invd(const int* __restrict__ S,
                                              float* __restrict__ invs) {
    int i = blockIdx.x * 256 + threadIdx.x;
    if (i < NC) {
        int d;
        if (i < 3 * NIV) { int b = i * NSI; d = S[b + NSI] - S[b]; }
        else             { int b = ITB + (i - 3 * NIV) * NSU; d = S[b + NSU] - S[b]; }
        invs[i] = (d > 0) ? (1.0f / sqrtf((float)d)) : 0.0f;
    }
}

// ---------------- fill CSR entries via precomputed ranks (no atomics) --------
__global__ __launch_bounds__(256) void k_fill(const int* __restrict__ e0,
                                              const int* __restrict__ e1,
                                              const int* __restrict__ e2,
                                              const float* __restrict__ invs,
                                              const int* __restrict__ S,
                                              const int* __restrict__ rk_i,
                                              const int* __restrict__ rk_u,
                                              float2* __restrict__ ent) {
    int k = blockIdx.y;
    const int* ed = (k == 0) ? e0 : (k == 1) ? e1 : e2;
    int e = blockIdx.x * 256 + threadIdx.x;
    if (e < EV) {
        int u = ed[e], i = ed[EV + e];
        float nm = invs[k * NIV + i] * invs[3 * NIV + k * NUV + u];
        int p1 = S[(k * NIV + i) * NSI + u / SLICE_DIV] + rk_i[(size_t)k * EV + e];
        ent[p1] = make_float2(__int_as_float(u), nm);
        int p2 = S[ITB + (k * NUV + u) * NSU + i / SLICE_DIV] + rk_u[(size_t)k * EV + e];
        ent[p2] = make_float2(__int_as_float(i), nm);
    }
}

// ---------------- sliced gather-aggregate + transform + hetero combine -------
// One dispatch per (layer, side). Block owns 32 dst nodes; subgroup (8 lanes)
// owns ONE node (all 3 relations), accumulating 3x8 fp32 in registers.
// OUTER LOOP = SOURCE SLICE: the whole GPU gathers from one 3.2MB L2-resident
// slice of the source table at a time -> L2-miss traffic ~= compulsory.
// After gather: sAcc in LDS, 256 threads transform (y_k = acc_k @ W_k + b_k,
// W from global L1-hot) and combine. MODE 0: relu(max), 1: sum. fp16 output.
template <int MODE, int NS, bool ITEM>
__global__ __launch_bounds__(256) void k_agg(const __half* __restrict__ x,
                                             const float2* __restrict__ ent,
                                             const int* __restrict__ S,
                                             const float* __restrict__ Wall,  // [6,64,64]
                                             const float* __restrict__ ball,  // [6,64]
                                             __half* __restrict__ outp) {
    __shared__ float sAcc[3][32][68];   // 26.1 KB (stride 68: bank pad)
    const float* Wb = ITEM ? Wall : Wall + 3 * 4096;
    const float* bb = ITEM ? ball : ball + 192;
    const int n_per = ITEM ? NIV : NUV;
    int d0 = blockIdx.x * 32;

    int sgid = threadIdx.x >> 3;      // 0..31 : node within block
    int ls   = threadIdx.x & 7;       // lane in subgroup: owns halves ls*8..+8
    int gi   = d0 + sgid;             // global node id

    // bucket bounds for this node's 3 relations: sb[k][0..NS]
    int sb[3][NS + 1];
    #pragma unroll
    for (int k = 0; k < 3; k++) {
        int b = ITEM ? (k * NIV + gi) * NS : (ITB + (k * n_per + gi) * NS);
        #pragma unroll
        for (int j = 0; j <= NS; j++) sb[k][j] = S[b + j];
    }

    float a[3][8];
    #pragma unroll
    for (int k = 0; k < 3; k++)
        #pragma unroll
        for (int j = 0; j < 8; j++) a[k][j] = 0.f;

    // slice-major gather: whole GPU works one source slice at a time
    for (int p = 0; p < NS; p++) {
        #pragma unroll
        for (int k = 0; k < 3; k++) {
            int st = sb[k][p], en = sb[k][p + 1];
            for (int base = st; base < en; base += 4) {
                float2 ee[4];
                #pragma unroll
                for (int j = 0; j < 4; j++) {
                    float2 e = make_float2(0.0f, 0.0f);
                    if (base + j < en) e = ent[base + j];
                    ee[j] = e;
                }
                float4 rr[4];
                #pragma unroll
                for (int j = 0; j < 4; j++) {
                    int s = __float_as_int(ee[j].x);
                    rr[j] = *(const float4*)(x + (size_t)s * 64 + ls * 8);
                }
                #pragma unroll
                for (int j = 0; j < 4; j++) {
                    float nm = ee[j].y;
                    const __half2* h2 = (const __half2*)&rr[j];
                    float2 f0 = __half22float2(h2[0]);
                    float2 f1 = __half22float2(h2[1]);
                    float2 f2 = __half22float2(h2[2]);
                    float2 f3 = __half22float2(h2[3]);
                    a[k][0] = fmaf(f0.x, nm, a[k][0]);
                    a[k][1] = fmaf(f0.y, nm, a[k][1]);
                    a[k][2] = fmaf(f1.x, nm, a[k][2]);
                    a[k][3] = fmaf(f1.y, nm, a[k][3]);
                    a[k][4] = fmaf(f2.x, nm, a[k][4]);
                    a[k][5] = fmaf(f2.y, nm, a[k][5]);
                    a[k][6] = fmaf(f3.x, nm, a[k][6]);
                    a[k][7] = fmaf(f3.y, nm, a[k][7]);
                }
            }
        }
    }
    #pragma unroll
    for (int k = 0; k < 3; k++) {
        *(float4*)&sAcc[k][sgid][ls * 8]     = make_float4(a[k][0], a[k][1], a[k][2], a[k][3]);
        *(float4*)&sAcc[k][sgid][ls * 8 + 4] = make_float4(a[k][4], a[k][5], a[k][6], a[k][7]);
    }
    __syncthreads();

    // transform + combine: two chunks of 16 rows
    int g = threadIdx.x & 15;          // col group (4 cols)
    #pragma unroll
    for (int half = 0; half < 2; half++) {
        int r = half * 16 + (threadIdx.x >> 4);
        float4 res = make_float4(0.f, 0.f, 0.f, 0.f);
        #pragma unroll
        for (int k = 0; k < 3; k++) {
            const float* Wk = Wb + (size_t)k * 4096;
            float4 y = *(const float4*)&bb[k * 64 + g * 4];
            #pragma unroll
            for (int c = 0; c < 64; c++) {
                float av = sAcc[k][r][c];
                float4 w = *(const float4*)&Wk[c * 64 + g * 4];
                y.x = fmaf(av, w.x, y.x);
                y.y = fmaf(av, w.y, y.y);
                y.z = fmaf(av, w.z, y.z);
                y.w = fmaf(av, w.w, y.w);
            }
            if (k == 0) {
                res = y;
            } else if (MODE == 0) {
                res.x = fmaxf(res.x, y.x); res.y = fmaxf(res.y, y.y);
                res.z = fmaxf(res.z, y.z); res.w = fmaxf(res.w, y.w);
            } else {
                res.x += y.x; res.y += y.y; res.z += y.z; res.w += y.w;
            }
        }
        if (MODE == 0) {
            res.x = fmaxf(res.x, 0.f); res.y = fmaxf(res.y, 0.f);
            res.z = fmaxf(res.z, 0.f); res.w = fmaxf(res.w, 0.f);
        }
        H4 o;
        o.a = __floats2half2_rn(res.x, res.y);
        o.b = __floats2half2_rn(res.z, res.w);
        *(H4*)(outp + (size_t)(d0 + r) * 64 + g * 4) = o;
    }
}

// ---------------- decoder: 16 queries per block, tile GEMM (fp16 inputs) -----
__global__ __launch_bounds__(256) void k_decoder(const __half* __restrict__ xu,
                                                 const __half* __restrict__ xi,
                                                 const int* __restrict__ uids,
                                                 const int* __restrict__ iids,
                                                 const float* __restrict__ w1,
                                                 const float* __restrict__ b1,
                                                 const float* __restrict__ w2,
                                                 const float* __restrict__ b2,
                                                 float* __restrict__ out) {
    __shared__ float sW1[128 * 64];   // 32 KB
    __shared__ float sE[16 * 132];
    __shared__ float sH[16 * 68];
    __shared__ float sW2[64 * 4];
    {
        const float4* wsrc = (const float4*)w1;
        float4* wdst = (float4*)sW1;
        #pragma unroll
        for (int i = 0; i < 8; i++) wdst[threadIdx.x + 256 * i] = wsrc[threadIdx.x + 256 * i];
        if (threadIdx.x < 64) {
            float4 v = ((const float4*)w2)[threadIdx.x];
            ((float4*)sW2)[threadIdx.x] = v;
        }
    }
    int q0 = blockIdx.x * 16;
    {
        int q = threadIdx.x >> 4;     // 0..15
        int p = threadIdx.x & 15;     // 0..15 -> 4 halves each
        int uid = uids[q0 + q];
        int iid = iids[q0 + q];
        H4 vu = *(const H4*)(xu + (size_t)uid * 64 + p * 4);
        H4 vi = *(const H4*)(xi + (size_t)iid * 64 + p * 4);
        float2 u0 = __half22float2(vu.a), u1 = __half22float2(vu.b);
        float2 i0 = __half22float2(vi.a), i1 = __half22float2(vi.b);
        *(float4*)&sE[q * 132 + p * 4] = make_float4(u0.x, u0.y, u1.x, u1.y);
        *(float4*)&sE[q * 132 + 64 + p * 4] = make_float4(i0.x, i0.y, i1.x, i1.y);
    }
    __syncthreads();
    {
        int r = threadIdx.x >> 4;
        int g = threadIdx.x & 15;
        float4 y = *(const float4*)&b1[g * 4];
        #pragma unroll
        for (int c = 0; c < 128; c++) {
            float a = sE[r * 132 + c];
            float4 w = *(const float4*)&sW1[c * 64 + g * 4];
            y.x = fmaf(a, w.x, y.x);
            y.y = fmaf(a, w.y, y.y);
            y.z = fmaf(a, w.z, y.z);
            y.w = fmaf(a, w.w, y.w);
        }
        y.x = fmaxf(y.x, 0.f); y.y = fmaxf(y.y, 0.f);
        y.z = fmaxf(y.z, 0.f); y.w = fmaxf(y.w, 0.f);
        *(float4*)&sH[r * 68 + g * 4] = y;
    }
    __syncthreads();
    if (threadIdx.x < 64) {
        int q = threadIdx.x >> 2;
        int oc = threadIdx.x & 3;
        float acc = b2[oc];
        #pragma unroll
        for (int c = 0; c < 64; c++)
            acc = fmaf(sH[q * 68 + c], sW2[c * 4 + oc], acc);
        out[(size_t)(q0 + q) * 4 + oc] = acc;
    }
}

extern "C" void kernel_launch(void* const* d_in, const int* in_sizes, int n_in,
                              void* d_out, int out_size, void* d_ws, size_t ws_size,
                              hipStream_t stream) {
    const float* user_emb = (const float*)d_in[0];
    const float* item_emb = (const float*)d_in[1];
    const float* W1 = (const float*)d_in[2];
    const float* b1 = (const float*)d_in[3];
    const float* W2 = (const float*)d_in[4];
    const float* b2 = (const float*)d_in[5];
    const float* dw1 = (const float*)d_in[6];
    const float* db1 = (const float*)d_in[7];
    const float* dw2 = (const float*)d_in[8];
    const float* db2 = (const float*)d_in[9];
    const int* e0 = (const int*)d_in[10];
    const int* e1 = (const int*)d_in[11];
    const int* e2 = (const int*)d_in[12];
    const int* uids = (const int*)d_in[13];
    const int* iids = (const int*)d_in[14];
    float* out = (float*)d_out;
    (void)in_sizes; (void)n_in; (void)out_size; (void)ws_size;

    // ---- workspace layout ----
    char* base = (char*)d_ws;
    size_t off = 0;
    int*    S    = (int*)(base + off);    off += (size_t)(TOTB + 16) * 4;   // 19.2MB
    int*    bsum = (int*)(base + off);    off += (size_t)20480 * 4;
    float*  invs = (float*)(base + off);  off += (size_t)NC * 4;            // 3.6MB
    float2* ent  = (float2*)(base + off); off += (size_t)EV6 * 8;           // 48MB
    __half* he_u = (__half*)(base + off); off += (size_t)NUV * 64 * 2;      // 25.6MB
    __half* he_i = (__half*)(base + off); off += (size_t)NIV * 64 * 2;      // 12.8MB
    __half* xu1h = (__half*)(base + off); off += (size_t)NUV * 64 * 2;
    __half* xi1h = (__half*)(base + off); off += (size_t)NIV * 64 * 2;
    // aliased scratch: {cnt, rki, rku} live during CSR build; {xu2h, xi2h}
    // live after k_fill completes (no overlap in time).
    char* scr = base + off;
    int*    cnt  = (int*)scr;                              // 19.2MB
    int*    rki  = (int*)(scr + (size_t)TOTB * 4);         // 12MB
    int*    rku  = rki + (size_t)3 * EV;                   // 12MB
    __half* xu2h = (__half*)scr;                           // 25.6MB
    __half* xi2h = xu2h + (size_t)NUV * 64;                // 12.8MB

    const int EB  = (EV + 255) / 256;        // 3907
    const int SCB = TOTB / 256;              // 18750 (exact)
    const int NCB = (NC + 255) / 256;        // 3516
    const int THB = ((NUV + NIV) * 16 + 255) / 256;

    // ---- fp16 feature tables ----
    k_tohalf<<<THB, 256, 0, stream>>>(user_emb, item_emb, he_u, he_i);

    // ---- sliced CSR build ----
    hipMemsetAsync(cnt, 0, (size_t)TOTB * 4, stream);
    k_count<<<dim3(EB, 3), 256, 0, stream>>>(e0, e1, e2, cnt, rki, rku);
    k_scan1<<<SCB, 256, 0, stream>>>(cnt, S, bsum);
    k_scan2<<<1, 64, 0, stream>>>(bsum, SCB);
    k_scan3<<<SCB, 256, 0, stream>>>(S, bsum);
    k_invd<<<NCB, 256, 0, stream>>>(S, invs);
    k_fill<<<dim3(EB, 3), 256, 0, stream>>>(e0, e1, e2, invs, S, rki, rku, ent);

    // ---- layer 1 (relu(max over rel)) ----
    k_agg<0, NSI, true ><<<NIV / 32, 256, 0, stream>>>(he_u, ent, S, W1, b1, xi1h);
    k_agg<0, NSU, false><<<NUV / 32, 256, 0, stream>>>(he_i, ent, S, W1, b1, xu1h);
    // ---- layer 2 (sum over rel) ----
    k_agg<1, NSI, true ><<<NIV / 32, 256, 0, stream>>>(xu1h, ent, S, W2, b2, xi2h);
    k_agg<1, NSU, false><<<NUV / 32, 256, 0, stream>>>(xi1h, ent, S, W2, b2, xu2h);

    // ---- decoder ----
    k_decoder<<<NQV / 16, 256, 0, stream>>>(xu2h, xi2h, uids, iids,
                                            dw1, db1, dw2, db2, out);
}